// Round 19
// baseline (64.262 us; speedup 1.0000x reference)
//
#include <hip/hip_runtime.h>
#include <math.h>

#define DIM   2048
#define NEXP  64
#define TPB   256
#define TOKB  32
#define NKS   32         // ksteps (K=32) per K-half

typedef float f32x4  __attribute__((ext_vector_type(4)));
typedef short bf16x8 __attribute__((ext_vector_type(8)));
typedef unsigned short u16;

#define MFMA __builtin_amdgcn_mfma_f32_16x16x32_bf16

// ---- software RNE bf16 (wconv only) ----
__device__ __forceinline__ u16 rne_bf16(float f) {
    union { float f; unsigned u; } v; v.f = f;
    unsigned u = v.u;
    u += 0x7fffu + ((u >> 16) & 1u);
    return (u16)(u >> 16);
}
__device__ __forceinline__ float bf2f(u16 h) {
    union { unsigned u; float f; } v; v.u = ((unsigned)h) << 16;
    return v.f;
}
__device__ __forceinline__ void split3(float x, u16& a, u16& b, u16& c) {
    a = rne_bf16(x);
    float r1 = x - bf2f(a);
    b = rne_bf16(r1);
    float r2 = r1 - bf2f(b);
    c = rne_bf16(r2);
}

// ---- hw packed cvt: D = {bf16(lo), bf16(hi)} in one instruction ----
__device__ __forceinline__ unsigned cvt_pk(float lo, float hi) {
    unsigned r;
    asm("v_cvt_pk_bf16_f32 %0, %1, %2" : "=v"(r) : "v"(lo), "v"(hi));
    return r;
}
__device__ __forceinline__ float lof(unsigned u) {
    union { unsigned u; float f; } v; v.u = u << 16;
    return v.f;
}
__device__ __forceinline__ float hif(unsigned u) {
    union { unsigned u; float f; } v; v.u = u & 0xffff0000u;
    return v.f;
}

// 8 floats -> 3 bf16x8 planes (3-term split, err ~2^-25: index-safe)
__device__ __forceinline__ void split3x8(f32x4 lo, f32x4 hi,
                                         bf16x8* A0, bf16x8* A1, bf16x8* A2) {
    unsigned w0[4], w1[4], w2[4];
    float e0[4] = {lo.x, lo.z, hi.x, hi.z};
    float e1[4] = {lo.y, lo.w, hi.y, hi.w};
#pragma unroll
    for (int j = 0; j < 4; ++j) {
        float a = e0[j], b = e1[j];
        unsigned p0 = cvt_pk(a, b);
        float r0 = a - lof(p0), r1 = b - hif(p0);
        unsigned p1 = cvt_pk(r0, r1);
        float s0 = r0 - lof(p1), s1 = r1 - hif(p1);
        w0[j] = p0; w1[j] = p1; w2[j] = cvt_pk(s0, s1);
    }
    *A0 = *(bf16x8*)w0;
    *A1 = *(bf16x8*)w1;
    *A2 = *(bf16x8*)w2;
}

#define GLD(GP, LP) __builtin_amdgcn_global_load_lds(                          \
        (const __attribute__((address_space(1))) unsigned*)(GP),               \
        (__attribute__((address_space(3))) unsigned*)(LP), 16, 0, 0)

// ---------------- Kernel 0: W -> 3 bf16 planes, MFMA-B-fragment-linear -------
// wp[kstep*12 + etile*3 + plane][lane][8];
// element: W[16*etile + (lane&15)][32*kstep + 8*(lane>>4) + i]
__global__ __launch_bounds__(256)
void wconv(const float* __restrict__ Wg, u16* __restrict__ wp) {
    const int G  = blockIdx.x * 256 + threadIdx.x;   // 0..16383
    const int l  = G & 63;
    const int r  = G >> 6;                           // kstep*4+etile
    const int ks = r >> 2, et = r & 3;
    const int ex = et * 16 + (l & 15);
    const int k  = ks * 32 + (l >> 4) * 8;
    const float* src = Wg + (size_t)ex * DIM + k;
    f32x4 v0 = *(const f32x4*)src;
    f32x4 v1 = *(const f32x4*)(src + 4);
    u16 h0[8], h1[8], h2[8];
#pragma unroll
    for (int i = 0; i < 8; ++i) {
        float xv = (i < 4) ? v0[i] : v1[i - 4];
        split3(xv, h0[i], h1[i], h2[i]);
    }
    u16* dst = wp + ((size_t)(ks * 12 + et * 3)) * 512 + l * 8;
    *(bf16x8*)(dst)        = *(bf16x8*)h0;
    *(bf16x8*)(dst + 512)  = *(bf16x8*)h1;
    *(bf16x8*)(dst + 1024) = *(bf16x8*)h2;
}

// ---------------- Kernel 1: barrier-free dedup'd MFMA router -----------------
// 32 tokens/block, 4 waves = 2 e-halves x 2 K-halves; grid 512 = 2 blocks/CU
// (decoupled: no barrier couples the CU's 8 waves). Each wave: 32 tok x 32 exp
// x K=1024; stages ONLY its own 6 B-frags/kstep (no duplication) into a
// wave-private LDS dbuf via global_load_lds; wave-private counted vmcnt.
__global__ __launch_bounds__(TPB, 2)
void router_main(const float* __restrict__ x, const u16* __restrict__ wp,
                 float* __restrict__ out, float* __restrict__ gCnt,
                 float* __restrict__ gPsum, int n_tokens) {
    __shared__ __align__(16) unsigned char smem[4 * 2 * 6 * 1024];  // 48 KB
    __shared__ float cnt[NEXP];
    __shared__ float rs[TOKB];
    u16 (*bq)[2][6][512] = (u16 (*)[2][6][512])smem;   // [wid][buf][frag][..]
    float (*ls)[TOKB][68] = (float (*)[TOKB][68])smem; // epilogue overlay 17.4KB

    const int tid  = threadIdx.x;
    const int lane = tid & 63;
    const int wid  = tid >> 6;       // 0..3
    const int eh   = wid & 1;        // expert half (32 experts)
    const int kh   = wid >> 1;       // K-half (1024)
    const int t0   = blockIdx.x * TOKB;

    if (tid < NEXP) cnt[tid] = 0.f;

    f32x4 acc[2][2];                 // [Atile][etile]
#pragma unroll
    for (int t2 = 0; t2 < 2; ++t2)
#pragma unroll
        for (int e2 = 0; e2 < 2; ++e2) acc[t2][e2] = (f32x4){0.f, 0.f, 0.f, 0.f};

    // A sources (verified layout): token row = base + (lane&15), k=8*(lane>>4)+i
    const float* xs0 = x + (size_t)(t0 + (lane & 15)) * DIM
                         + kh * (NKS * 32) + 8 * (lane >> 4);
    const float* xs1 = xs0 + (size_t)16 * DIM;

    // wave stages rows [g*12 + 6*eh, +6) of wp into its private dbuf
#define STAGEB(C) do {                                                         \
        const int g_ = kh * NKS + (C);                                         \
        const u16* gp_ = wp + ((size_t)g_ * 12 + 6 * eh) * 512 + lane * 8;     \
        _Pragma("unroll")                                                      \
        for (int f = 0; f < 6; ++f)                                            \
            GLD(gp_ + (size_t)f * 512, &bq[wid][(C) & 1][f][0]);               \
    } while (0)

#define LOADX(S0, S1, S2, S3, C) do {                                          \
        S0 = *(const f32x4*)(xs0 + (C) * 32);                                  \
        S1 = *(const f32x4*)(xs0 + (C) * 32 + 4);                              \
        S2 = *(const f32x4*)(xs1 + (C) * 32);                                  \
        S3 = *(const f32x4*)(xs1 + (C) * 32 + 4);                              \
    } while (0)

    // per kstep: wait own vmcnt -> 6 ds_read -> split3 -> lgkm fence ->
    // issue c+2 (B DMA + x regs) -> 24 MFMA. Depth-2, no barriers.
#define ITER(C, S0, S1, S2, S3) do {                                           \
        if ((C) + 1 < NKS) asm volatile("s_waitcnt vmcnt(10)" ::: "memory");   \
        else               asm volatile("s_waitcnt vmcnt(0)"  ::: "memory");   \
        __builtin_amdgcn_sched_barrier(0);                                     \
        bf16x8 B00 = *(const bf16x8*)&bq[wid][(C) & 1][0][lane * 8];           \
        bf16x8 B01 = *(const bf16x8*)&bq[wid][(C) & 1][1][lane * 8];           \
        bf16x8 B02 = *(const bf16x8*)&bq[wid][(C) & 1][2][lane * 8];           \
        bf16x8 B10 = *(const bf16x8*)&bq[wid][(C) & 1][3][lane * 8];           \
        bf16x8 B11 = *(const bf16x8*)&bq[wid][(C) & 1][4][lane * 8];           \
        bf16x8 B12 = *(const bf16x8*)&bq[wid][(C) & 1][5][lane * 8];           \
        bf16x8 A00, A01, A02, A10, A11, A12;                                   \
        split3x8(S0, S1, &A00, &A01, &A02);                                    \
        split3x8(S2, S3, &A10, &A11, &A12);                                    \
        asm volatile("s_waitcnt lgkmcnt(0)" ::: "memory");                     \
        __builtin_amdgcn_sched_barrier(0);                                     \
        if ((C) + 2 < NKS) { STAGEB((C) + 2); LOADX(S0, S1, S2, S3, (C) + 2); }\
        acc[0][0] = MFMA(A00, B00, acc[0][0], 0, 0, 0);                        \
        acc[0][0] = MFMA(A00, B01, acc[0][0], 0, 0, 0);                        \
        acc[0][0] = MFMA(A01, B00, acc[0][0], 0, 0, 0);                        \
        acc[0][0] = MFMA(A01, B01, acc[0][0], 0, 0, 0);                        \
        acc[0][0] = MFMA(A00, B02, acc[0][0], 0, 0, 0);                        \
        acc[0][0] = MFMA(A02, B00, acc[0][0], 0, 0, 0);                        \
        acc[0][1] = MFMA(A00, B10, acc[0][1], 0, 0, 0);                        \
        acc[0][1] = MFMA(A00, B11, acc[0][1], 0, 0, 0);                        \
        acc[0][1] = MFMA(A01, B10, acc[0][1], 0, 0, 0);                        \
        acc[0][1] = MFMA(A01, B11, acc[0][1], 0, 0, 0);                        \
        acc[0][1] = MFMA(A00, B12, acc[0][1], 0, 0, 0);                        \
        acc[0][1] = MFMA(A02, B10, acc[0][1], 0, 0, 0);                        \
        acc[1][0] = MFMA(A10, B00, acc[1][0], 0, 0, 0);                        \
        acc[1][0] = MFMA(A10, B01, acc[1][0], 0, 0, 0);                        \
        acc[1][0] = MFMA(A11, B00, acc[1][0], 0, 0, 0);                        \
        acc[1][0] = MFMA(A11, B01, acc[1][0], 0, 0, 0);                        \
        acc[1][0] = MFMA(A10, B02, acc[1][0], 0, 0, 0);                        \
        acc[1][0] = MFMA(A12, B00, acc[1][0], 0, 0, 0);                        \
        acc[1][1] = MFMA(A10, B10, acc[1][1], 0, 0, 0);                        \
        acc[1][1] = MFMA(A10, B11, acc[1][1], 0, 0, 0);                        \
        acc[1][1] = MFMA(A11, B10, acc[1][1], 0, 0, 0);                        \
        acc[1][1] = MFMA(A11, B11, acc[1][1], 0, 0, 0);                        \
        acc[1][1] = MFMA(A10, B12, acc[1][1], 0, 0, 0);                        \
        acc[1][1] = MFMA(A12, B10, acc[1][1], 0, 0, 0);                        \
    } while (0)

    f32x4 pa0, pa1, pa2, pa3, pb0, pb1, pb2, pb3;
    STAGEB(0);
    LOADX(pa0, pa1, pa2, pa3, 0);
    STAGEB(1);
    LOADX(pb0, pb1, pb2, pb3, 1);

    for (int cc = 0; cc < NKS; cc += 2) {
        ITER(cc,     pa0, pa1, pa2, pa3);
        ITER(cc + 1, pb0, pb1, pb2, pb3);
    }
#undef ITER
#undef LOADX
#undef STAGEB

    __syncthreads();   // all waves done (own vmcnt drained); bq dead

    // ---- partial logits -> overlay (C layout verified: col=lane&15,
    //      row=4*(lane>>4)+r); indexed by K-half for the reduce
    {
        const int e0 = lane & 15;
#pragma unroll
        for (int t2 = 0; t2 < 2; ++t2) {
            const int mr = 16 * t2 + 4 * (lane >> 4);
#pragma unroll
            for (int r = 0; r < 4; ++r) {
                ls[kh][mr + r][32 * eh + e0]      = acc[t2][0][r];
                ls[kh][mr + r][32 * eh + 16 + e0] = acc[t2][1][r];
            }
        }
    }
    __syncthreads();

    // ---- reduce 2 K-halves (256 threads x 2 f32x4) ----
#pragma unroll
    for (int r2 = 0; r2 < 2; ++r2) {
        const int idx = tid + TPB * r2;     // 0..511
        const int tk  = idx >> 4;           // 0..31
        const int e4  = (idx & 15) * 4;
        f32x4 v = *(const f32x4*)&ls[0][tk][e4];
        v = v + *(const f32x4*)&ls[1][tk][e4];
        *(f32x4*)&ls[0][tk][e4] = v;
    }
    __syncthreads();

    // ---- per-token top-2 + softmax: 8 threads per token ----
    const int tok = tid >> 3;           // 0..31
    const int sub = tid & 7;
    float l8[8];
#pragma unroll
    for (int j = 0; j < 8; ++j) l8[j] = ls[0][tok][sub * 8 + j];
    float m1 = -1e30f, m2 = -1e30f;
    int   i1 = 0, i2 = 0;
#pragma unroll
    for (int j = 0; j < 8; ++j) {
        float v = l8[j]; int e = sub * 8 + j;
        if (v > m1)      { m2 = m1; i2 = i1; m1 = v; i1 = e; }
        else if (v > m2) { m2 = v; i2 = e; }
    }
#pragma unroll
    for (int off = 1; off < 8; off <<= 1) {
        float n1 = __shfl_xor(m1, off, 8); int j1 = __shfl_xor(i1, off, 8);
        float n2 = __shfl_xor(m2, off, 8); int j2 = __shfl_xor(i2, off, 8);
        bool fb = (m1 > n1) || (m1 == n1 && i1 < j1);   // ties: lower index
        float a1 = fb ? m1 : n1;  int ai = fb ? i1 : j1;
        float b1 = fb ? n1 : m1;  int bi = fb ? j1 : i1;
        float c2 = fb ? m2 : n2;  int ci = fb ? i2 : j2;
        bool bb = (b1 > c2) || (b1 == c2 && bi < ci);
        m1 = a1; i1 = ai;
        m2 = bb ? b1 : c2; i2 = bb ? bi : ci;
    }
    float psum = 0.f;
#pragma unroll
    for (int j = 0; j < 8; ++j) {
        float p = __expf(l8[j] - m1);
        psum += p;
        ls[0][tok][sub * 8 + j] = p;    // unnormalized probs
    }
#pragma unroll
    for (int off = 1; off < 8; off <<= 1) psum += __shfl_xor(psum, off, 8);
    const float inv = 1.f / psum;
    if (sub == 0) {
        rs[tok] = inv;
        const float p1 = inv;                     // exp(0)*inv
        const float p2 = __expf(m2 - m1) * inv;
        const float d  = p1 + p2 + 1e-8f;
        const int tg = t0 + tok;
        out[(size_t)tg * 2]     = (float)i1;
        out[(size_t)tg * 2 + 1] = (float)i2;
        out[(size_t)n_tokens * 2 + (size_t)tg * 2]     = p1 / d;
        out[(size_t)n_tokens * 2 + (size_t)tg * 2 + 1] = p2 / d;
        atomicAdd(&cnt[i1], 1.f);
        atomicAdd(&cnt[i2], 1.f);
    }
    __syncthreads();

    // ---- per-expert column sums + global accumulation ----
    if (tid < NEXP) {
        float cs = 0.f;
#pragma unroll 8
        for (int t = 0; t < TOKB; ++t) cs += ls[0][t][tid] * rs[t];
        atomicAdd(&gPsum[tid], cs);
        atomicAdd(&gCnt[tid], cnt[tid]);
    }
}

// ---------------- Kernel 2: final aux loss -----------------------------------
__global__ void router_aux(const float* __restrict__ gCnt,
                           const float* __restrict__ gPsum,
                           float* __restrict__ out, int n_tokens) {
    const int e = threadIdx.x;
    float f = gCnt[e] / (float)(n_tokens * 2);
    float P = gPsum[e] / (float)n_tokens;
    float v = f * P;
#pragma unroll
    for (int o = 32; o > 0; o >>= 1) v += __shfl_down(v, o);
    if (e == 0) out[(size_t)n_tokens * 4] = 64.f * v;
}

extern "C" void kernel_launch(void* const* d_in, const int* in_sizes, int n_in,
                              void* d_out, int out_size, void* d_ws, size_t ws_size,
                              hipStream_t stream) {
    const float* x  = (const float*)d_in[0];
    const float* Wg = (const float*)d_in[1];
    float* out = (float*)d_out;
    const int n_tokens = in_sizes[0] / DIM;   // 16384

    // ws layout: wplanes (256*3*512 u16 = 786 KB), then gCnt/gPsum
    u16*   wplanes = (u16*)d_ws;
    float* gCnt    = (float*)((char*)d_ws + 256 * 3 * 512 * sizeof(u16));
    float* gPsum   = gCnt + NEXP;

    hipMemsetAsync(gCnt, 0, 2 * NEXP * sizeof(float), stream);
    hipLaunchKernelGGL(wconv, dim3(64), dim3(256), 0, stream, Wg, wplanes);
    hipLaunchKernelGGL(router_main, dim3(n_tokens / TOKB), dim3(TPB), 0, stream,
                       x, wplanes, out, gCnt, gPsum, n_tokens);
    hipLaunchKernelGGL(router_aux, dim3(1), dim3(NEXP), 0, stream,
                       gCnt, gPsum, out, n_tokens);
}

// Round 20
// 50.459 us; speedup vs baseline: 1.2735x; 1.2735x over previous
//
#include <hip/hip_runtime.h>
#include <math.h>

#define DIM   2048
#define NEXP  64
#define TPB   256        // 4 waves
#define TOKB  64
#define KSQ   16         // ksteps (K=32) per K-quarter

typedef float f32x4  __attribute__((ext_vector_type(4)));
typedef short bf16x8 __attribute__((ext_vector_type(8)));
typedef unsigned short u16;

#define MFMA __builtin_amdgcn_mfma_f32_16x16x32_bf16

// ---- software RNE bf16 (wconv only) ----
__device__ __forceinline__ u16 rne_bf16(float f) {
    union { float f; unsigned u; } v; v.f = f;
    unsigned u = v.u;
    u += 0x7fffu + ((u >> 16) & 1u);
    return (u16)(u >> 16);
}
__device__ __forceinline__ float bf2f(u16 h) {
    union { unsigned u; float f; } v; v.u = ((unsigned)h) << 16;
    return v.f;
}
__device__ __forceinline__ void split3(float x, u16& a, u16& b, u16& c) {
    a = rne_bf16(x);
    float r1 = x - bf2f(a);
    b = rne_bf16(r1);
    float r2 = r1 - bf2f(b);
    c = rne_bf16(r2);
}

// ---- hw packed cvt ----
__device__ __forceinline__ unsigned cvt_pk(float lo, float hi) {
    unsigned r;
    asm("v_cvt_pk_bf16_f32 %0, %1, %2" : "=v"(r) : "v"(lo), "v"(hi));
    return r;
}
__device__ __forceinline__ float lof(unsigned u) {
    union { unsigned u; float f; } v; v.u = u << 16;
    return v.f;
}
__device__ __forceinline__ float hif(unsigned u) {
    union { unsigned u; float f; } v; v.u = u & 0xffff0000u;
    return v.f;
}

// 8 floats -> 3 bf16x8 planes (3-term split, err ~2^-25: index-safe)
__device__ __forceinline__ void split3x8(f32x4 lo, f32x4 hi,
                                         bf16x8* A0, bf16x8* A1, bf16x8* A2) {
    unsigned w0[4], w1[4], w2[4];
    float e0[4] = {lo.x, lo.z, hi.x, hi.z};
    float e1[4] = {lo.y, lo.w, hi.y, hi.w};
#pragma unroll
    for (int j = 0; j < 4; ++j) {
        float a = e0[j], b = e1[j];
        unsigned p0 = cvt_pk(a, b);
        float r0 = a - lof(p0), r1 = b - hif(p0);
        unsigned p1 = cvt_pk(r0, r1);
        float s0 = r0 - lof(p1), s1 = r1 - hif(p1);
        w0[j] = p0; w1[j] = p1; w2[j] = cvt_pk(s0, s1);
    }
    *A0 = *(bf16x8*)w0;
    *A1 = *(bf16x8*)w1;
    *A2 = *(bf16x8*)w2;
}

#define GLD(GP, LP) __builtin_amdgcn_global_load_lds(                          \
        (const __attribute__((address_space(1))) unsigned*)(GP),               \
        (__attribute__((address_space(3))) unsigned*)(LP), 16, 0, 0)

// ---------------- Kernel 0: W -> 3 bf16 planes, MFMA-B-fragment-linear -------
// wp[kstep*12 + etile*3 + plane][lane][8];
// element: W[16*etile + (lane&15)][32*kstep + 8*(lane>>4) + i]
__global__ __launch_bounds__(256)
void wconv(const float* __restrict__ Wg, u16* __restrict__ wp) {
    const int G  = blockIdx.x * 256 + threadIdx.x;   // 0..16383
    const int l  = G & 63;
    const int r  = G >> 6;                           // kstep*4+etile
    const int ks = r >> 2, et = r & 3;
    const int ex = et * 16 + (l & 15);
    const int k  = ks * 32 + (l >> 4) * 8;
    const float* src = Wg + (size_t)ex * DIM + k;
    f32x4 v0 = *(const f32x4*)src;
    f32x4 v1 = *(const f32x4*)(src + 4);
    u16 h0[8], h1[8], h2[8];
#pragma unroll
    for (int i = 0; i < 8; ++i) {
        float xv = (i < 4) ? v0[i] : v1[i - 4];
        split3(xv, h0[i], h1[i], h2[i]);
    }
    u16* dst = wp + ((size_t)(ks * 12 + et * 3)) * 512 + l * 8;
    *(bf16x8*)(dst)        = *(bf16x8*)h0;
    *(bf16x8*)(dst + 512)  = *(bf16x8*)h1;
    *(bf16x8*)(dst + 1024) = *(bf16x8*)h2;
}

// ---------------- Kernel 1: fat-wave barrier-free MFMA router ----------------
// 64 tokens/block, 4 waves = 4 K-quarters; grid 256 = 1 block/CU (1 wave/SIMD,
// intended). Each wave: 64 tok x 64 exp x K=512 fully independent — per kstep:
// deterministic vmcnt(20) wait, 12 ds_read, 96 MFMA (8:1 MFMA:read), then
// re-stage (12 GLD + 8 x-loads = exactly 20 vm-ops). ZERO main-loop barriers.
__global__ __launch_bounds__(TPB, 1)
void router_main(const float* __restrict__ x, const u16* __restrict__ wp,
                 float* __restrict__ out, float* __restrict__ gCnt,
                 float* __restrict__ gPsum, int n_tokens) {
    __shared__ __align__(16) unsigned char smem[4 * 2 * 12 * 1024];  // 96 KB
    __shared__ float cnt[NEXP];
    __shared__ float rs[TOKB];
    u16 (*bq)[2][12][512] = (u16 (*)[2][12][512])smem;   // [kq][buf][frag][..]
    float (*ls)[TOKB][68] = (float (*)[TOKB][68])smem;   // overlay 69.6 KB

    const int tid  = threadIdx.x;
    const int lane = tid & 63;
    const int kq   = tid >> 6;       // wave = K-quarter 0..3
    const int t0   = blockIdx.x * TOKB;

    if (tid < NEXP) cnt[tid] = 0.f;

    f32x4 acc[4][4];                 // [Atile][etile] — static idx only
#pragma unroll
    for (int t = 0; t < 4; ++t)
#pragma unroll
        for (int e = 0; e < 4; ++e) acc[t][e] = (f32x4){0.f, 0.f, 0.f, 0.f};

    // A sources (verified layout): row = t0+16t+(lane&15), k = 8*(lane>>4)+i
    const float* xt0 = x + (size_t)(t0 +  0 + (lane & 15)) * DIM
                         + kq * (KSQ * 32) + 8 * (lane >> 4);
    const float* xt1 = xt0 + (size_t)16 * DIM;
    const float* xt2 = xt0 + (size_t)32 * DIM;
    const float* xt3 = xt0 + (size_t)48 * DIM;

    // stage kstep C's 12 B-frags into private dbuf (12 GLD, uniform LDS base)
#define STAGEB(C) do {                                                         \
        const int g_ = kq * KSQ + (C);                                         \
        const u16* gp_ = wp + ((size_t)g_ * 12) * 512 + lane * 8;              \
        _Pragma("unroll")                                                      \
        for (int j = 0; j < 12; ++j)                                           \
            GLD(gp_ + (size_t)j * 512, &bq[kq][(C) & 1][j][0]);                \
    } while (0)

    // 8 x-loads (f32x4) for kstep C into a named register set
#define LOADX(P0, P1, P2, P3, P4, P5, P6, P7, C) do {                          \
        P0 = *(const f32x4*)(xt0 + (C) * 32);                                  \
        P1 = *(const f32x4*)(xt0 + (C) * 32 + 4);                              \
        P2 = *(const f32x4*)(xt1 + (C) * 32);                                  \
        P3 = *(const f32x4*)(xt1 + (C) * 32 + 4);                              \
        P4 = *(const f32x4*)(xt2 + (C) * 32);                                  \
        P5 = *(const f32x4*)(xt2 + (C) * 32 + 4);                              \
        P6 = *(const f32x4*)(xt3 + (C) * 32);                                  \
        P7 = *(const f32x4*)(xt3 + (C) * 32 + 4);                              \
    } while (0)

    // one etile: 3 ds_read_b128 + 24 MFMA against 4 A-tiles
#define ETILE(E, C) do {                                                       \
        bf16x8 B0 = *(const bf16x8*)&bq[kq][(C) & 1][(E) * 3 + 0][lane * 8];   \
        bf16x8 B1 = *(const bf16x8*)&bq[kq][(C) & 1][(E) * 3 + 1][lane * 8];   \
        bf16x8 B2 = *(const bf16x8*)&bq[kq][(C) & 1][(E) * 3 + 2][lane * 8];   \
        acc[0][E] = MFMA(A00, B0, acc[0][E], 0, 0, 0);                         \
        acc[0][E] = MFMA(A00, B1, acc[0][E], 0, 0, 0);                         \
        acc[0][E] = MFMA(A01, B0, acc[0][E], 0, 0, 0);                         \
        acc[0][E] = MFMA(A01, B1, acc[0][E], 0, 0, 0);                         \
        acc[0][E] = MFMA(A00, B2, acc[0][E], 0, 0, 0);                         \
        acc[0][E] = MFMA(A02, B0, acc[0][E], 0, 0, 0);                         \
        acc[1][E] = MFMA(A10, B0, acc[1][E], 0, 0, 0);                         \
        acc[1][E] = MFMA(A10, B1, acc[1][E], 0, 0, 0);                         \
        acc[1][E] = MFMA(A11, B0, acc[1][E], 0, 0, 0);                         \
        acc[1][E] = MFMA(A11, B1, acc[1][E], 0, 0, 0);                         \
        acc[1][E] = MFMA(A10, B2, acc[1][E], 0, 0, 0);                         \
        acc[1][E] = MFMA(A12, B0, acc[1][E], 0, 0, 0);                         \
        acc[2][E] = MFMA(A20, B0, acc[2][E], 0, 0, 0);                         \
        acc[2][E] = MFMA(A20, B1, acc[2][E], 0, 0, 0);                         \
        acc[2][E] = MFMA(A21, B0, acc[2][E], 0, 0, 0);                         \
        acc[2][E] = MFMA(A21, B1, acc[2][E], 0, 0, 0);                         \
        acc[2][E] = MFMA(A20, B2, acc[2][E], 0, 0, 0);                         \
        acc[2][E] = MFMA(A22, B0, acc[2][E], 0, 0, 0);                         \
        acc[3][E] = MFMA(A30, B0, acc[3][E], 0, 0, 0);                         \
        acc[3][E] = MFMA(A30, B1, acc[3][E], 0, 0, 0);                         \
        acc[3][E] = MFMA(A31, B0, acc[3][E], 0, 0, 0);                         \
        acc[3][E] = MFMA(A31, B1, acc[3][E], 0, 0, 0);                         \
        acc[3][E] = MFMA(A30, B2, acc[3][E], 0, 0, 0);                         \
        acc[3][E] = MFMA(A32, B0, acc[3][E], 0, 0, 0);                         \
    } while (0)

    // per kstep: deterministic wait -> split3 -> 4x etile -> retire reads ->
    // re-stage (exactly 20 vm-ops). No barriers; wave self-paced.
#define ITER(C, P0, P1, P2, P3, P4, P5, P6, P7) do {                           \
        if ((C) + 1 < KSQ) asm volatile("s_waitcnt vmcnt(20)" ::: "memory");   \
        else               asm volatile("s_waitcnt vmcnt(0)"  ::: "memory");   \
        __builtin_amdgcn_sched_barrier(0);                                     \
        bf16x8 A00, A01, A02, A10, A11, A12, A20, A21, A22, A30, A31, A32;     \
        split3x8(P0, P1, &A00, &A01, &A02);                                    \
        split3x8(P2, P3, &A10, &A11, &A12);                                    \
        split3x8(P4, P5, &A20, &A21, &A22);                                    \
        split3x8(P6, P7, &A30, &A31, &A32);                                    \
        ETILE(0, C);                                                           \
        ETILE(1, C);                                                           \
        ETILE(2, C);                                                           \
        ETILE(3, C);                                                           \
        asm volatile("s_waitcnt lgkmcnt(0)" ::: "memory");                     \
        __builtin_amdgcn_sched_barrier(0);                                     \
        if ((C) + 2 < KSQ) {                                                   \
            STAGEB((C) + 2);                                                   \
            LOADX(P0, P1, P2, P3, P4, P5, P6, P7, (C) + 2);                    \
        }                                                                      \
    } while (0)

    f32x4 pa0, pa1, pa2, pa3, pa4, pa5, pa6, pa7;
    f32x4 pb0, pb1, pb2, pb3, pb4, pb5, pb6, pb7;
    STAGEB(0);
    LOADX(pa0, pa1, pa2, pa3, pa4, pa5, pa6, pa7, 0);
    STAGEB(1);
    LOADX(pb0, pb1, pb2, pb3, pb4, pb5, pb6, pb7, 1);

    for (int cc = 0; cc < KSQ; cc += 2) {
        ITER(cc,     pa0, pa1, pa2, pa3, pa4, pa5, pa6, pa7);
        ITER(cc + 1, pb0, pb1, pb2, pb3, pb4, pb5, pb6, pb7);
    }
#undef ITER
#undef ETILE
#undef LOADX
#undef STAGEB

    __syncthreads();   // all waves done; bq dead -> overlay logits

    // ---- partial logits -> overlay (C layout verified: col=lane&15,
    //      row=4*(lane>>4)+r), indexed by K-quarter for the reduce
    {
        const int e0 = lane & 15;
#pragma unroll
        for (int t = 0; t < 4; ++t) {
            const int mr = 16 * t + 4 * (lane >> 4);
#pragma unroll
            for (int r = 0; r < 4; ++r) {
                ls[kq][mr + r][e0]      = acc[t][0][r];
                ls[kq][mr + r][e0 + 16] = acc[t][1][r];
                ls[kq][mr + r][e0 + 32] = acc[t][2][r];
                ls[kq][mr + r][e0 + 48] = acc[t][3][r];
            }
        }
    }
    __syncthreads();

    // ---- reduce 4 K-quarters (256 threads x 4 f32x4) ----
#pragma unroll
    for (int r2 = 0; r2 < 4; ++r2) {
        const int idx = tid + TPB * r2;     // 0..1023
        const int tk  = idx >> 4;           // 0..63
        const int e4  = (idx & 15) * 4;
        f32x4 v = *(const f32x4*)&ls[0][tk][e4];
        v = v + *(const f32x4*)&ls[1][tk][e4];
        v = v + *(const f32x4*)&ls[2][tk][e4];
        v = v + *(const f32x4*)&ls[3][tk][e4];
        *(f32x4*)&ls[0][tk][e4] = v;
    }
    __syncthreads();

    // ---- per-token top-2 + softmax: 4 threads per token (verified R15) ----
    const int tok = tid >> 2;           // 0..63
    const int sub = tid & 3;
    float l16[16];
#pragma unroll
    for (int j = 0; j < 16; ++j) l16[j] = ls[0][tok][sub * 16 + j];
    float m1 = -1e30f, m2 = -1e30f;
    int   i1 = 0, i2 = 0;
#pragma unroll
    for (int j = 0; j < 16; ++j) {
        float v = l16[j]; int e = sub * 16 + j;
        if (v > m1)      { m2 = m1; i2 = i1; m1 = v; i1 = e; }
        else if (v > m2) { m2 = v; i2 = e; }
    }
#pragma unroll
    for (int off = 1; off < 4; off <<= 1) {
        float n1 = __shfl_xor(m1, off, 4); int j1 = __shfl_xor(i1, off, 4);
        float n2 = __shfl_xor(m2, off, 4); int j2 = __shfl_xor(i2, off, 4);
        bool fb = (m1 > n1) || (m1 == n1 && i1 < j1);   // ties: lower index
        float a1 = fb ? m1 : n1;  int ai = fb ? i1 : j1;
        float b1 = fb ? n1 : m1;  int bi = fb ? j1 : i1;
        float c2 = fb ? m2 : n2;  int ci = fb ? i2 : j2;
        bool bb = (b1 > c2) || (b1 == c2 && bi < ci);
        m1 = a1; i1 = ai;
        m2 = bb ? b1 : c2; i2 = bb ? bi : ci;
    }
    float psum = 0.f;
#pragma unroll
    for (int j = 0; j < 16; ++j) {
        float pv = __expf(l16[j] - m1);
        psum += pv;
        ls[0][tok][sub * 16 + j] = pv;   // unnormalized probs
    }
#pragma unroll
    for (int off = 1; off < 4; off <<= 1) psum += __shfl_xor(psum, off, 4);
    const float inv = 1.f / psum;
    if (sub == 0) {
        rs[tok] = inv;
        const float p1 = inv;                     // exp(0)*inv
        const float p2 = __expf(m2 - m1) * inv;
        const float d  = p1 + p2 + 1e-8f;
        const int tg = t0 + tok;
        out[(size_t)tg * 2]     = (float)i1;
        out[(size_t)tg * 2 + 1] = (float)i2;
        out[(size_t)n_tokens * 2 + (size_t)tg * 2]     = p1 / d;
        out[(size_t)n_tokens * 2 + (size_t)tg * 2 + 1] = p2 / d;
        atomicAdd(&cnt[i1], 1.f);
        atomicAdd(&cnt[i2], 1.f);
    }
    __syncthreads();

    // ---- per-expert column sums + global accumulation ----
    if (tid < NEXP) {
        float cs = 0.f;
#pragma unroll 8
        for (int t = 0; t < TOKB; ++t) cs += ls[0][t][tid] * rs[t];
        atomicAdd(&gPsum[tid], cs);
        atomicAdd(&gCnt[tid], cnt[tid]);
    }
}

// ---------------- Kernel 2: final aux loss -----------------------------------
__global__ void router_aux(const float* __restrict__ gCnt,
                           const float* __restrict__ gPsum,
                           float* __restrict__ out, int n_tokens) {
    const int e = threadIdx.x;
    float f = gCnt[e] / (float)(n_tokens * 2);
    float P = gPsum[e] / (float)n_tokens;
    float v = f * P;
#pragma unroll
    for (int o = 32; o > 0; o >>= 1) v += __shfl_down(v, o);
    if (e == 0) out[(size_t)n_tokens * 4] = 64.f * v;
}

extern "C" void kernel_launch(void* const* d_in, const int* in_sizes, int n_in,
                              void* d_out, int out_size, void* d_ws, size_t ws_size,
                              hipStream_t stream) {
    const float* x  = (const float*)d_in[0];
    const float* Wg = (const float*)d_in[1];
    float* out = (float*)d_out;
    const int n_tokens = in_sizes[0] / DIM;   // 16384

    // ws layout: wplanes (256*3*512 u16 = 786 KB), then gCnt/gPsum
    u16*   wplanes = (u16*)d_ws;
    float* gCnt    = (float*)((char*)d_ws + 256 * 3 * 512 * sizeof(u16));
    float* gPsum   = gCnt + NEXP;

    hipMemsetAsync(gCnt, 0, 2 * NEXP * sizeof(float), stream);
    hipLaunchKernelGGL(wconv, dim3(64), dim3(256), 0, stream, Wg, wplanes);
    hipLaunchKernelGGL(router_main, dim3(n_tokens / TOKB), dim3(TPB), 0, stream,
                       x, wplanes, out, gCnt, gPsum, n_tokens);
    hipLaunchKernelGGL(router_aux, dim3(1), dim3(NEXP), 0, stream,
                       gCnt, gPsum, out, n_tokens);
}

// Round 21
// 49.971 us; speedup vs baseline: 1.2860x; 1.0098x over previous
//
#include <hip/hip_runtime.h>
#include <math.h>

#define DIM   2048
#define NEXP  64
#define TPB   256        // 4 waves
#define TOKB  64
#define KSQ   16         // ksteps (K=32) per K-quarter

typedef float f32x4  __attribute__((ext_vector_type(4)));
typedef short bf16x8 __attribute__((ext_vector_type(8)));
typedef unsigned short u16;

#define MFMA __builtin_amdgcn_mfma_f32_16x16x32_bf16

// ---- software RNE bf16 (wconv only) ----
__device__ __forceinline__ u16 rne_bf16(float f) {
    union { float f; unsigned u; } v; v.f = f;
    unsigned u = v.u;
    u += 0x7fffu + ((u >> 16) & 1u);
    return (u16)(u >> 16);
}
__device__ __forceinline__ float bf2f(u16 h) {
    union { unsigned u; float f; } v; v.u = ((unsigned)h) << 16;
    return v.f;
}
__device__ __forceinline__ void split3(float x, u16& a, u16& b, u16& c) {
    a = rne_bf16(x);
    float r1 = x - bf2f(a);
    b = rne_bf16(r1);
    float r2 = r1 - bf2f(b);
    c = rne_bf16(r2);
}

// ---- hw packed cvt ----
__device__ __forceinline__ unsigned cvt_pk(float lo, float hi) {
    unsigned r;
    asm("v_cvt_pk_bf16_f32 %0, %1, %2" : "=v"(r) : "v"(lo), "v"(hi));
    return r;
}
__device__ __forceinline__ float lof(unsigned u) {
    union { unsigned u; float f; } v; v.u = u << 16;
    return v.f;
}
__device__ __forceinline__ float hif(unsigned u) {
    union { unsigned u; float f; } v; v.u = u & 0xffff0000u;
    return v.f;
}

// 8 floats -> 3 bf16x8 planes (3-term split, err ~2^-25: index-safe)
__device__ __forceinline__ void split3x8(f32x4 lo, f32x4 hi,
                                         bf16x8* A0, bf16x8* A1, bf16x8* A2) {
    unsigned w0[4], w1[4], w2[4];
    float e0[4] = {lo.x, lo.z, hi.x, hi.z};
    float e1[4] = {lo.y, lo.w, hi.y, hi.w};
#pragma unroll
    for (int j = 0; j < 4; ++j) {
        float a = e0[j], b = e1[j];
        unsigned p0 = cvt_pk(a, b);
        float r0 = a - lof(p0), r1 = b - hif(p0);
        unsigned p1 = cvt_pk(r0, r1);
        float s0 = r0 - lof(p1), s1 = r1 - hif(p1);
        w0[j] = p0; w1[j] = p1; w2[j] = cvt_pk(s0, s1);
    }
    *A0 = *(bf16x8*)w0;
    *A1 = *(bf16x8*)w1;
    *A2 = *(bf16x8*)w2;
}

#define GLD(GP, LP) __builtin_amdgcn_global_load_lds(                          \
        (const __attribute__((address_space(1))) unsigned*)(GP),               \
        (__attribute__((address_space(3))) unsigned*)(LP), 16, 0, 0)

// ---------------- Kernel 0: W -> 3 bf16 planes, MFMA-B-fragment-linear -------
// wp[kstep*12 + etile*3 + plane][lane][8];
// element: W[16*etile + (lane&15)][32*kstep + 8*(lane>>4) + i]
__global__ __launch_bounds__(256)
void wconv(const float* __restrict__ Wg, u16* __restrict__ wp) {
    const int G  = blockIdx.x * 256 + threadIdx.x;   // 0..16383
    const int l  = G & 63;
    const int r  = G >> 6;                           // kstep*4+etile
    const int ks = r >> 2, et = r & 3;
    const int ex = et * 16 + (l & 15);
    const int k  = ks * 32 + (l >> 4) * 8;
    const float* src = Wg + (size_t)ex * DIM + k;
    f32x4 v0 = *(const f32x4*)src;
    f32x4 v1 = *(const f32x4*)(src + 4);
    u16 h0[8], h1[8], h2[8];
#pragma unroll
    for (int i = 0; i < 8; ++i) {
        float xv = (i < 4) ? v0[i] : v1[i - 4];
        split3(xv, h0[i], h1[i], h2[i]);
    }
    u16* dst = wp + ((size_t)(ks * 12 + et * 3)) * 512 + l * 8;
    *(bf16x8*)(dst)        = *(bf16x8*)h0;
    *(bf16x8*)(dst + 512)  = *(bf16x8*)h1;
    *(bf16x8*)(dst + 1024) = *(bf16x8*)h2;
}

// ---------------- Kernel 1: fat-wave barrier-free MFMA router ----------------
// Identical structure to R19 (best: 50.5us). Re-scheduled kstep body:
// all 12 B ds_reads hoisted before split3 (latency under VALU), and MFMAs
// emitted PRODUCT-MAJOR so consecutive MFMAs hit 16 distinct acc chains
// (dep distance 16 vs 4).
__global__ __launch_bounds__(TPB, 1)
void router_main(const float* __restrict__ x, const u16* __restrict__ wp,
                 float* __restrict__ out, float* __restrict__ gCnt,
                 float* __restrict__ gPsum, int n_tokens) {
    __shared__ __align__(16) unsigned char smem[4 * 2 * 12 * 1024];  // 96 KB
    __shared__ float cnt[NEXP];
    __shared__ float rs[TOKB];
    u16 (*bq)[2][12][512] = (u16 (*)[2][12][512])smem;   // [kq][buf][frag][..]
    float (*ls)[TOKB][68] = (float (*)[TOKB][68])smem;   // overlay 69.6 KB

    const int tid  = threadIdx.x;
    const int lane = tid & 63;
    const int kq   = tid >> 6;       // wave = K-quarter 0..3
    const int t0   = blockIdx.x * TOKB;

    if (tid < NEXP) cnt[tid] = 0.f;

    f32x4 acc[4][4];                 // [Atile][etile] — static idx only
#pragma unroll
    for (int t = 0; t < 4; ++t)
#pragma unroll
        for (int e = 0; e < 4; ++e) acc[t][e] = (f32x4){0.f, 0.f, 0.f, 0.f};

    // A sources (verified layout): row = t0+16t+(lane&15), k = 8*(lane>>4)+i
    const float* xt0 = x + (size_t)(t0 +  0 + (lane & 15)) * DIM
                         + kq * (KSQ * 32) + 8 * (lane >> 4);
    const float* xt1 = xt0 + (size_t)16 * DIM;
    const float* xt2 = xt0 + (size_t)32 * DIM;
    const float* xt3 = xt0 + (size_t)48 * DIM;

    // stage kstep C's 12 B-frags into private dbuf (12 GLD, uniform LDS base)
#define STAGEB(C) do {                                                         \
        const int g_ = kq * KSQ + (C);                                         \
        const u16* gp_ = wp + ((size_t)g_ * 12) * 512 + lane * 8;              \
        _Pragma("unroll")                                                      \
        for (int j = 0; j < 12; ++j)                                           \
            GLD(gp_ + (size_t)j * 512, &bq[kq][(C) & 1][j][0]);                \
    } while (0)

    // 8 x-loads (f32x4) for kstep C into a named register set
#define LOADX(P0, P1, P2, P3, P4, P5, P6, P7, C) do {                          \
        P0 = *(const f32x4*)(xt0 + (C) * 32);                                  \
        P1 = *(const f32x4*)(xt0 + (C) * 32 + 4);                              \
        P2 = *(const f32x4*)(xt1 + (C) * 32);                                  \
        P3 = *(const f32x4*)(xt1 + (C) * 32 + 4);                              \
        P4 = *(const f32x4*)(xt2 + (C) * 32);                                  \
        P5 = *(const f32x4*)(xt2 + (C) * 32 + 4);                              \
        P6 = *(const f32x4*)(xt3 + (C) * 32);                                  \
        P7 = *(const f32x4*)(xt3 + (C) * 32 + 4);                              \
    } while (0)

    // per kstep: wait -> 12 B ds_reads (hoisted) -> split3 (covers ds lat) ->
    // 96 MFMA product-major (16 indep chains) -> retire reads -> re-stage.
#define ITER(C, P0, P1, P2, P3, P4, P5, P6, P7) do {                           \
        if ((C) + 1 < KSQ) asm volatile("s_waitcnt vmcnt(20)" ::: "memory");   \
        else               asm volatile("s_waitcnt vmcnt(0)"  ::: "memory");   \
        __builtin_amdgcn_sched_barrier(0);                                     \
        bf16x8 Bf[4][3];                                                       \
        _Pragma("unroll")                                                      \
        for (int et = 0; et < 4; ++et)                                         \
            _Pragma("unroll")                                                  \
            for (int p = 0; p < 3; ++p)                                        \
                Bf[et][p] = *(const bf16x8*)&bq[kq][(C) & 1][et * 3 + p][lane * 8]; \
        bf16x8 Af[4][3];                                                       \
        split3x8(P0, P1, &Af[0][0], &Af[0][1], &Af[0][2]);                     \
        split3x8(P2, P3, &Af[1][0], &Af[1][1], &Af[1][2]);                     \
        split3x8(P4, P5, &Af[2][0], &Af[2][1], &Af[2][2]);                     \
        split3x8(P6, P7, &Af[3][0], &Af[3][1], &Af[3][2]);                     \
        _Pragma("unroll")                                                      \
        for (int pr = 0; pr < 6; ++pr) {                                       \
            constexpr int PA[6] = {0, 0, 1, 1, 0, 2};                          \
            constexpr int PB[6] = {0, 1, 0, 1, 2, 0};                          \
            _Pragma("unroll")                                                  \
            for (int et = 0; et < 4; ++et)                                     \
                _Pragma("unroll")                                              \
                for (int t = 0; t < 4; ++t)                                    \
                    acc[t][et] = MFMA(Af[t][PA[pr]], Bf[et][PB[pr]],           \
                                      acc[t][et], 0, 0, 0);                    \
        }                                                                      \
        asm volatile("s_waitcnt lgkmcnt(0)" ::: "memory");                     \
        __builtin_amdgcn_sched_barrier(0);                                     \
        if ((C) + 2 < KSQ) {                                                   \
            STAGEB((C) + 2);                                                   \
            LOADX(P0, P1, P2, P3, P4, P5, P6, P7, (C) + 2);                    \
        }                                                                      \
    } while (0)

    f32x4 pa0, pa1, pa2, pa3, pa4, pa5, pa6, pa7;
    f32x4 pb0, pb1, pb2, pb3, pb4, pb5, pb6, pb7;
    STAGEB(0);
    LOADX(pa0, pa1, pa2, pa3, pa4, pa5, pa6, pa7, 0);
    STAGEB(1);
    LOADX(pb0, pb1, pb2, pb3, pb4, pb5, pb6, pb7, 1);

    for (int cc = 0; cc < KSQ; cc += 2) {
        ITER(cc,     pa0, pa1, pa2, pa3, pa4, pa5, pa6, pa7);
        ITER(cc + 1, pb0, pb1, pb2, pb3, pb4, pb5, pb6, pb7);
    }
#undef ITER
#undef LOADX
#undef STAGEB

    __syncthreads();   // all waves done; bq dead -> overlay logits

    // ---- partial logits -> overlay (C layout verified: col=lane&15,
    //      row=4*(lane>>4)+r), indexed by K-quarter for the reduce
    {
        const int e0 = lane & 15;
#pragma unroll
        for (int t = 0; t < 4; ++t) {
            const int mr = 16 * t + 4 * (lane >> 4);
#pragma unroll
            for (int r = 0; r < 4; ++r) {
                ls[kq][mr + r][e0]      = acc[t][0][r];
                ls[kq][mr + r][e0 + 16] = acc[t][1][r];
                ls[kq][mr + r][e0 + 32] = acc[t][2][r];
                ls[kq][mr + r][e0 + 48] = acc[t][3][r];
            }
        }
    }
    __syncthreads();

    // ---- reduce 4 K-quarters (256 threads x 4 f32x4) ----
#pragma unroll
    for (int r2 = 0; r2 < 4; ++r2) {
        const int idx = tid + TPB * r2;     // 0..1023
        const int tk  = idx >> 4;           // 0..63
        const int e4  = (idx & 15) * 4;
        f32x4 v = *(const f32x4*)&ls[0][tk][e4];
        v = v + *(const f32x4*)&ls[1][tk][e4];
        v = v + *(const f32x4*)&ls[2][tk][e4];
        v = v + *(const f32x4*)&ls[3][tk][e4];
        *(f32x4*)&ls[0][tk][e4] = v;
    }
    __syncthreads();

    // ---- per-token top-2 + softmax: 4 threads per token (verified) ----
    const int tok = tid >> 2;           // 0..63
    const int sub = tid & 3;
    float l16[16];
#pragma unroll
    for (int j = 0; j < 16; ++j) l16[j] = ls[0][tok][sub * 16 + j];
    float m1 = -1e30f, m2 = -1e30f;
    int   i1 = 0, i2 = 0;
#pragma unroll
    for (int j = 0; j < 16; ++j) {
        float v = l16[j]; int e = sub * 16 + j;
        if (v > m1)      { m2 = m1; i2 = i1; m1 = v; i1 = e; }
        else if (v > m2) { m2 = v; i2 = e; }
    }
#pragma unroll
    for (int off = 1; off < 4; off <<= 1) {
        float n1 = __shfl_xor(m1, off, 4); int j1 = __shfl_xor(i1, off, 4);
        float n2 = __shfl_xor(m2, off, 4); int j2 = __shfl_xor(i2, off, 4);
        bool fb = (m1 > n1) || (m1 == n1 && i1 < j1);   // ties: lower index
        float a1 = fb ? m1 : n1;  int ai = fb ? i1 : j1;
        float b1 = fb ? n1 : m1;  int bi = fb ? j1 : i1;
        float c2 = fb ? m2 : n2;  int ci = fb ? i2 : j2;
        bool bb = (b1 > c2) || (b1 == c2 && bi < ci);
        m1 = a1; i1 = ai;
        m2 = bb ? b1 : c2; i2 = bb ? bi : ci;
    }
    float psum = 0.f;
#pragma unroll
    for (int j = 0; j < 16; ++j) {
        float pv = __expf(l16[j] - m1);
        psum += pv;
        ls[0][tok][sub * 16 + j] = pv;   // unnormalized probs
    }
#pragma unroll
    for (int off = 1; off < 4; off <<= 1) psum += __shfl_xor(psum, off, 4);
    const float inv = 1.f / psum;
    if (sub == 0) {
        rs[tok] = inv;
        const float p1 = inv;                     // exp(0)*inv
        const float p2 = __expf(m2 - m1) * inv;
        const float d  = p1 + p2 + 1e-8f;
        const int tg = t0 + tok;
        out[(size_t)tg * 2]     = (float)i1;
        out[(size_t)tg * 2 + 1] = (float)i2;
        out[(size_t)n_tokens * 2 + (size_t)tg * 2]     = p1 / d;
        out[(size_t)n_tokens * 2 + (size_t)tg * 2 + 1] = p2 / d;
        atomicAdd(&cnt[i1], 1.f);
        atomicAdd(&cnt[i2], 1.f);
    }
    __syncthreads();

    // ---- per-expert column sums + global accumulation ----
    if (tid < NEXP) {
        float cs = 0.f;
#pragma unroll 8
        for (int t = 0; t < TOKB; ++t) cs += ls[0][t][tid] * rs[t];
        atomicAdd(&gPsum[tid], cs);
        atomicAdd(&gCnt[tid], cnt[tid]);
    }
}

// ---------------- Kernel 2: final aux loss -----------------------------------
__global__ void router_aux(const float* __restrict__ gCnt,
                           const float* __restrict__ gPsum,
                           float* __restrict__ out, int n_tokens) {
    const int e = threadIdx.x;
    float f = gCnt[e] / (float)(n_tokens * 2);
    float P = gPsum[e] / (float)n_tokens;
    float v = f * P;
#pragma unroll
    for (int o = 32; o > 0; o >>= 1) v += __shfl_down(v, o);
    if (e == 0) out[(size_t)n_tokens * 4] = 64.f * v;
}

extern "C" void kernel_launch(void* const* d_in, const int* in_sizes, int n_in,
                              void* d_out, int out_size, void* d_ws, size_t ws_size,
                              hipStream_t stream) {
    const float* x  = (const float*)d_in[0];
    const float* Wg = (const float*)d_in[1];
    float* out = (float*)d_out;
    const int n_tokens = in_sizes[0] / DIM;   // 16384

    // ws layout: wplanes (256*3*512 u16 = 786 KB), then gCnt/gPsum
    u16*   wplanes = (u16*)d_ws;
    float* gCnt    = (float*)((char*)d_ws + 256 * 3 * 512 * sizeof(u16));
    float* gPsum   = gCnt + NEXP;

    hipMemsetAsync(gCnt, 0, 2 * NEXP * sizeof(float), stream);
    hipLaunchKernelGGL(wconv, dim3(64), dim3(256), 0, stream, Wg, wplanes);
    hipLaunchKernelGGL(router_main, dim3(n_tokens / TOKB), dim3(TPB), 0, stream,
                       x, wplanes, out, gCnt, gPsum, n_tokens);
    hipLaunchKernelGGL(router_aux, dim3(1), dim3(NEXP), 0, stream,
                       gCnt, gPsum, out, n_tokens);
}